// Round 1
// baseline (7353.601 us; speedup 1.0000x reference)
//
#include <hip/hip_runtime.h>
#include <math.h>

#define TS 512
#define NB 64
#define NF 64
#define NE 256
#define NH 512
#define NG 2048
#define NO 128

#define NGRP 16   // batch groups (4 rows each)
#define NSLC 16   // gate slices per group
#define RPG  4    // rows per group
#define GPW  128  // gate-rows per WG (4 gate types x 32 h-idx)
#define HS   516  // h_lds row stride (floats), 16B-aligned, conflict-free

// ws layout (float words)
#define OFF_WCOMB 0        // 2048*64
#define OFF_BCOMB 131072   // 2048
#define OFF_HBUF  133120   // 2*64*512
#define OFF_POOL  198656   // 64*512
#define OFF_CNT   231424   // 16*512 ints

__global__ __launch_bounds__(256) void k_zero(int* __restrict__ cnt) {
    int i = blockIdx.x * 256 + threadIdx.x;
    if (i < NGRP * TS) cnt[i] = 0;
}

// W_comb[g][f] = sum_e W_ih[g][e] * W_emb[e][f];  b_comb[g] = W_ih[g]·b_emb + b_ih[g] + b_hh[g]
__global__ __launch_bounds__(256) void k_wcomb(const float* __restrict__ W_emb,
                                               const float* __restrict__ b_emb,
                                               const float* __restrict__ W_ih,
                                               const float* __restrict__ b_ih,
                                               const float* __restrict__ b_hh,
                                               float* __restrict__ W_comb,
                                               float* __restrict__ b_comb) {
    __shared__ float wih[4][NE];
    int g0 = blockIdx.x * 4;
    for (int i = threadIdx.x; i < 4 * NE; i += 256)
        wih[i >> 8][i & 255] = W_ih[(size_t)g0 * NE + i];
    __syncthreads();
    int gl = threadIdx.x >> 6, f = threadIdx.x & 63;
    float acc = 0.f;
    for (int e = 0; e < NE; ++e) acc += wih[gl][e] * W_emb[e * NF + f];
    W_comb[(size_t)(g0 + gl) * NF + f] = acc;
    if (f == 0) {
        float a2 = 0.f;
        for (int e = 0; e < NE; ++e) a2 += wih[gl][e] * b_emb[e];
        b_comb[g0 + gl] = a2 + b_ih[g0 + gl] + b_hh[g0 + gl];
    }
}

// Persistent LSTM recurrence. Grid 256 WGs x 512 thr.
// WG = (grp = blockIdx%16 -> batch rows 4*grp..+4, slc = blockIdx/16 -> h-idx [32*slc,+32))
// Each thread permanently holds 128 floats of W_hh (gate-row x 128-k chunk).
__global__ __launch_bounds__(512, 2) void k_lstm(const float* __restrict__ x,
                                                 const float* __restrict__ W_hh,
                                                 const float* __restrict__ W_comb,
                                                 const float* __restrict__ b_comb,
                                                 float* __restrict__ hbuf,
                                                 float* __restrict__ pooled,
                                                 int* __restrict__ cnt) {
    const int wg = blockIdx.x;
    const int grp = wg & 15;
    const int slc = wg >> 4;
    const int tid = threadIdx.x;
    const int lane = tid & 63, wave = tid >> 6;
    const int gh = wave & 1, q = wave >> 1;      // q: k-chunk [128q,+128)
    const int g = gh * 64 + lane;                // gate-row local [0,128)
    const int Gt = g >> 5, j = g & 31;
    const int hh = slc * 32 + j;
    const int R = Gt * NH + hh;                  // W_hh global row
    const int kb = q * 128;

    __shared__ __align__(16) float h_lds[RPG * HS];
    __shared__ __align__(16) float part[4 * GPW * 4];   // [q][g][r]
    __shared__ float gact[512];                         // [g][r]
    __shared__ __align__(16) float xl[2][RPG][68];
    __shared__ __align__(16) float wcomb[GPW][68];
    __shared__ float bcl[GPW];

    // permanent W_hh fragment
    float4 wreg[32];
    {
        const float* wrow = W_hh + (size_t)R * NH + kb;
        #pragma unroll
        for (int i = 0; i < 32; ++i) wreg[i] = ((const float4*)wrow)[i];
    }
    // W_comb slice + b_comb slice
    for (int i = tid; i < GPW * NF; i += 512) {
        int gg = i >> 6, ff = i & 63;
        int Rg = (gg >> 5) * NH + slc * 32 + (gg & 31);
        wcomb[gg][ff] = W_comb[(size_t)Rg * NF + ff];
    }
    if (tid < GPW) {
        int Rg = (tid >> 5) * NH + slc * 32 + (tid & 31);
        bcl[tid] = b_comb[Rg];
    }
    // x[t=0]
    if (tid < RPG * NF) {
        int r = tid >> 6, k = tid & 63;
        xl[0][r][k] = x[((size_t)(grp * RPG + r) * TS + 0) * NF + k];
    }
    float c_reg = 0.f, hsum = 0.f;  // live on tid<128
    __syncthreads();

    for (int t = 0; t < TS; ++t) {
        if (t > 0) {
            if (tid == 0) {
                int guard = 0;
                while (__hip_atomic_load(&cnt[grp * TS + (t - 1)], __ATOMIC_ACQUIRE,
                                         __HIP_MEMORY_SCOPE_AGENT) < NSLC) {
                    __builtin_amdgcn_s_sleep(1);
                    if (++guard > (1 << 22)) break;  // anti-hang escape
                }
            }
            __syncthreads();
            // stage h(t-1) -> LDS
            {
                int r = tid >> 7, k4 = (tid & 127) << 2;
                const float* hp = hbuf + ((size_t)((t - 1) & 1) * NB + grp * RPG + r) * NH + k4;
                #pragma unroll
                for (int i = 0; i < 4; ++i)
                    h_lds[r * HS + k4 + i] =
                        __hip_atomic_load(hp + i, __ATOMIC_RELAXED, __HIP_MEMORY_SCOPE_AGENT);
            }
        } else {
            for (int i = tid; i < RPG * HS; i += 512) h_lds[i] = 0.f;
        }
        // prefetch x[t+1] (independent of h)
        float xpre = 0.f; int xr = 0, xk = 0;
        if (t + 1 < TS && tid < RPG * NF) {
            xr = tid >> 6; xk = tid & 63;
            xpre = x[((size_t)(grp * RPG + xr) * TS + (t + 1)) * NF + xk];
        }
        __syncthreads();

        // partial dots: acc[r] = W_hh[R][kb..kb+128] · h[r][kb..kb+128]
        float a0 = 0.f, a1 = 0.f, a2 = 0.f, a3 = 0.f;
        #pragma unroll
        for (int i = 0; i < 32; ++i) {
            const float4 wv = wreg[i];
            const int k = kb + 4 * i;
            const float4 h0 = *(const float4*)&h_lds[0 * HS + k];
            const float4 h1 = *(const float4*)&h_lds[1 * HS + k];
            const float4 h2 = *(const float4*)&h_lds[2 * HS + k];
            const float4 h3 = *(const float4*)&h_lds[3 * HS + k];
            a0 += wv.x * h0.x + wv.y * h0.y + wv.z * h0.z + wv.w * h0.w;
            a1 += wv.x * h1.x + wv.y * h1.y + wv.z * h1.z + wv.w * h1.w;
            a2 += wv.x * h2.x + wv.y * h2.y + wv.z * h2.z + wv.w * h2.w;
            a3 += wv.x * h3.x + wv.y * h3.y + wv.z * h3.z + wv.w * h3.w;
        }
        ((float4*)part)[q * GPW + g] = make_float4(a0, a1, a2, a3);
        if (t + 1 < TS && tid < RPG * NF) xl[(t + 1) & 1][xr][xk] = xpre;
        __syncthreads();

        // reduce over q + x-projection + bias + activation; thread -> (g2 = tid>>2, r2 = tid&3)
        {
            const int g2 = tid >> 2, r2 = tid & 3;
            float v = part[0 * 512 + tid] + part[1 * 512 + tid] +
                      part[2 * 512 + tid] + part[3 * 512 + tid];
            const float* xrow = &xl[t & 1][r2][0];
            const float* wrow = &wcomb[g2][0];
            float s = 0.f;
            #pragma unroll
            for (int kk = 0; kk < NF; kk += 4) {
                const float4 xv = *(const float4*)(xrow + kk);
                const float4 wv = *(const float4*)(wrow + kk);
                s += xv.x * wv.x + xv.y * wv.y + xv.z * wv.z + xv.w * wv.w;
            }
            v += s + bcl[g2];
            float a;
            if ((g2 >> 5) == 2) a = tanhf(v);               // cell gate
            else                a = 1.f / (1.f + __expf(-v)); // i,f,o
            gact[tid] = a;
        }
        __syncthreads();

        // c/h update on tid<128: (r2 = tid&3, j2 = tid>>2)
        if (tid < 128) {
            const int r2 = tid & 3, j2 = tid >> 2;
            const float iv = gact[0 + tid], fv = gact[128 + tid];
            const float gv = gact[256 + tid], ov = gact[384 + tid];
            c_reg = fv * c_reg + iv * gv;
            const float h = ov * tanhf(c_reg);
            hsum += h;
            __hip_atomic_store(&hbuf[((size_t)(t & 1) * NB + grp * RPG + r2) * NH + slc * 32 + j2],
                               h, __ATOMIC_RELAXED, __HIP_MEMORY_SCOPE_AGENT);
        }
        __syncthreads();  // drains the h stores (vmcnt) for all threads
        if (tid == 0) {
            __threadfence();
            __hip_atomic_fetch_add(&cnt[grp * TS + t], 1, __ATOMIC_RELEASE,
                                   __HIP_MEMORY_SCOPE_AGENT);
        }
    }

    if (tid < 128) {
        const int r2 = tid & 3, j2 = tid >> 2;
        pooled[(size_t)(grp * RPG + r2) * NH + slc * 32 + j2] = hsum * (1.f / TS);
    }
}

// out[b][o] = pooled[b]·W_fc[o] + b_fc[o]
__global__ __launch_bounds__(256) void k_fc(const float* __restrict__ pooled,
                                            const float* __restrict__ W_fc,
                                            const float* __restrict__ b_fc,
                                            float* __restrict__ out) {
    __shared__ float pl[2][NH];
    const int b0 = blockIdx.x * 2;
    for (int i = threadIdx.x; i < 2 * NH; i += 256)
        pl[i >> 9][i & 511] = pooled[(size_t)b0 * NH + i];
    __syncthreads();
    const int o = threadIdx.x & 127, bl = threadIdx.x >> 7;
    const float* wr = W_fc + (size_t)o * NH;
    float acc = 0.f;
    #pragma unroll 4
    for (int k = 0; k < NH; k += 4) {
        const float4 wv = *(const float4*)&wr[k];
        acc += pl[bl][k] * wv.x + pl[bl][k + 1] * wv.y +
               pl[bl][k + 2] * wv.z + pl[bl][k + 3] * wv.w;
    }
    out[(size_t)(b0 + bl) * NO + o] = acc + b_fc[o];
}

extern "C" void kernel_launch(void* const* d_in, const int* in_sizes, int n_in,
                              void* d_out, int out_size, void* d_ws, size_t ws_size,
                              hipStream_t stream) {
    const float* x     = (const float*)d_in[0];
    const float* W_emb = (const float*)d_in[1];
    const float* b_emb = (const float*)d_in[2];
    const float* W_ih  = (const float*)d_in[3];
    const float* W_hh  = (const float*)d_in[4];
    const float* b_ih  = (const float*)d_in[5];
    const float* b_hh  = (const float*)d_in[6];
    const float* W_fc  = (const float*)d_in[7];
    const float* b_fc  = (const float*)d_in[8];
    float* out = (float*)d_out;
    float* ws  = (float*)d_ws;

    float* W_comb = ws + OFF_WCOMB;
    float* b_comb = ws + OFF_BCOMB;
    float* hbuf   = ws + OFF_HBUF;
    float* pooled = ws + OFF_POOL;
    int*   cnt    = (int*)(ws + OFF_CNT);

    hipLaunchKernelGGL(k_zero,  dim3(32),  dim3(256), 0, stream, cnt);
    hipLaunchKernelGGL(k_wcomb, dim3(512), dim3(256), 0, stream,
                       W_emb, b_emb, W_ih, b_ih, b_hh, W_comb, b_comb);
    hipLaunchKernelGGL(k_lstm,  dim3(256), dim3(512), 0, stream,
                       x, W_hh, W_comb, b_comb, hbuf, pooled, cnt);
    hipLaunchKernelGGL(k_fc,    dim3(32),  dim3(256), 0, stream,
                       pooled, W_fc, b_fc, out);
}

// Round 2
// 4580.167 us; speedup vs baseline: 1.6055x; 1.6055x over previous
//
#include <hip/hip_runtime.h>
#include <math.h>

#define TS 512
#define NB 64
#define NF 64
#define NE 256
#define NH 512
#define NG 2048
#define NO 128

#define NGRP 16   // batch groups (4 rows each)
#define NSLC 16   // gate slices per group
#define RPG  4    // rows per group
#define GPW  128  // gate-rows per WG (4 gate types x 32 h-idx)
#define HS   516  // h_lds row stride (floats), 16B-aligned, conflict-free

// ws layout (float words)
#define OFF_WCOMB 0        // 2048*64
#define OFF_BCOMB 131072   // 2048
#define OFF_HBUF  133120   // 2*64*512
#define OFF_POOL  198656   // 64*512
#define OFF_CNT   231424   // 16*512 ints

__device__ __forceinline__ float fast_sigmoid(float v) {
    return 1.f / (1.f + __expf(-v));
}
__device__ __forceinline__ float fast_tanh(float v) {
    // tanh(v) = 2*sigmoid(2v) - 1 ; __expf handles overflow to +inf -> result +/-1
    return 1.f - 2.f / (1.f + __expf(2.f * v));
}

__global__ __launch_bounds__(256) void k_zero(int* __restrict__ cnt) {
    int i = blockIdx.x * 256 + threadIdx.x;
    if (i < NGRP * TS) cnt[i] = 0;
}

// W_comb[g][f] = sum_e W_ih[g][e] * W_emb[e][f];  b_comb[g] = W_ih[g]·b_emb + b_ih[g] + b_hh[g]
__global__ __launch_bounds__(256) void k_wcomb(const float* __restrict__ W_emb,
                                               const float* __restrict__ b_emb,
                                               const float* __restrict__ W_ih,
                                               const float* __restrict__ b_ih,
                                               const float* __restrict__ b_hh,
                                               float* __restrict__ W_comb,
                                               float* __restrict__ b_comb) {
    __shared__ float wih[4][NE];
    int g0 = blockIdx.x * 4;
    for (int i = threadIdx.x; i < 4 * NE; i += 256)
        wih[i >> 8][i & 255] = W_ih[(size_t)g0 * NE + i];
    __syncthreads();
    int gl = threadIdx.x >> 6, f = threadIdx.x & 63;
    float acc = 0.f;
    for (int e = 0; e < NE; ++e) acc += wih[gl][e] * W_emb[e * NF + f];
    W_comb[(size_t)(g0 + gl) * NF + f] = acc;
    if (f == 0) {
        float a2 = 0.f;
        for (int e = 0; e < NE; ++e) a2 += wih[gl][e] * b_emb[e];
        b_comb[g0 + gl] = a2 + b_ih[g0 + gl] + b_hh[g0 + gl];
    }
}

// Persistent LSTM recurrence. Grid 256 WGs x 512 thr.
// Sync design (R2): relaxed-atomic flag counter per (grp,t), capacity 2*NSLC=32
// (each WG's two h-writer waves publish independently after their own
// s_waitcnt vmcnt(0)). No ACQUIRE spin loads (no per-poll buffer_inv), no
// __threadfence (no buffer_wbl2). h exchange itself uses agent-scope relaxed
// atomics which bypass L1/L2 to the coherent point, so no cache maintenance
// is needed for correctness.
__global__ __launch_bounds__(512, 2) void k_lstm(const float* __restrict__ x,
                                                 const float* __restrict__ W_hh,
                                                 const float* __restrict__ W_comb,
                                                 const float* __restrict__ b_comb,
                                                 float* __restrict__ hbuf,
                                                 float* __restrict__ pooled,
                                                 int* __restrict__ cnt) {
    const int wg = blockIdx.x;
    const int grp = wg & 15;
    const int slc = wg >> 4;
    const int tid = threadIdx.x;
    const int lane = tid & 63, wave = tid >> 6;
    const int gh = wave & 1, q = wave >> 1;      // q: k-chunk [128q,+128)
    const int g = gh * 64 + lane;                // gate-row local [0,128)
    const int Gt = g >> 5, j = g & 31;
    const int hh = slc * 32 + j;
    const int R = Gt * NH + hh;                  // W_hh global row
    const int kb = q * 128;

    __shared__ __align__(16) float h_lds[RPG * HS];
    __shared__ __align__(16) float part[4 * GPW * 4];   // [q][g][r]
    __shared__ float gact[512];                         // [g][r]
    __shared__ __align__(16) float xl[2][RPG][68];
    __shared__ __align__(16) float wcomb[GPW][68];
    __shared__ float bcl[GPW];

    // permanent W_hh fragment
    float4 wreg[32];
    {
        const float* wrow = W_hh + (size_t)R * NH + kb;
        #pragma unroll
        for (int i = 0; i < 32; ++i) wreg[i] = ((const float4*)wrow)[i];
    }
    // W_comb slice + b_comb slice
    for (int i = tid; i < GPW * NF; i += 512) {
        int gg = i >> 6, ff = i & 63;
        int Rg = (gg >> 5) * NH + slc * 32 + (gg & 31);
        wcomb[gg][ff] = W_comb[(size_t)Rg * NF + ff];
    }
    if (tid < GPW) {
        int Rg = (tid >> 5) * NH + slc * 32 + (tid & 31);
        bcl[tid] = b_comb[Rg];
    }
    // x[t=0]
    if (tid < RPG * NF) {
        int r = tid >> 6, k = tid & 63;
        xl[0][r][k] = x[((size_t)(grp * RPG + r) * TS + 0) * NF + k];
    }
    float c_reg = 0.f, hsum = 0.f;  // live on tid<128
    __syncthreads();

    for (int t = 0; t < TS; ++t) {
        if (t > 0) {
            // every wave's lane 0 spins (RELAXED — no cache maintenance)
            if ((tid & 63) == 0) {
                int guard = 0;
                while (__hip_atomic_load(&cnt[grp * TS + (t - 1)], __ATOMIC_RELAXED,
                                         __HIP_MEMORY_SCOPE_AGENT) < 2 * NSLC) {
                    __builtin_amdgcn_s_sleep(1);
                    if (++guard > (1 << 21)) break;  // anti-hang escape
                }
            }
            __builtin_amdgcn_fence(__ATOMIC_ACQUIRE, "workgroup");
            // stage h(t-1) -> LDS (2x u64 bypass loads -> float4 LDS write)
            {
                int r = tid >> 7, k4 = (tid & 127) << 2;
                const unsigned long long* hp = (const unsigned long long*)
                    (hbuf + ((size_t)((t - 1) & 1) * NB + grp * RPG + r) * NH + k4);
                union { unsigned long long u[2]; float4 f; } hv;
                hv.u[0] = __hip_atomic_load(hp + 0, __ATOMIC_RELAXED, __HIP_MEMORY_SCOPE_AGENT);
                hv.u[1] = __hip_atomic_load(hp + 1, __ATOMIC_RELAXED, __HIP_MEMORY_SCOPE_AGENT);
                *(float4*)&h_lds[r * HS + k4] = hv.f;
            }
        } else {
            for (int i = tid; i < RPG * HS; i += 512) h_lds[i] = 0.f;
        }
        // prefetch x[t+1] (independent of h)
        float xpre = 0.f; int xr = 0, xk = 0;
        if (t + 1 < TS && tid < RPG * NF) {
            xr = tid >> 6; xk = tid & 63;
            xpre = x[((size_t)(grp * RPG + xr) * TS + (t + 1)) * NF + xk];
        }
        __syncthreads();  // #1: h_lds ready

        // partial dots: acc[r] = W_hh[R][kb..kb+128] · h[r][kb..kb+128]
        float a0 = 0.f, a1 = 0.f, a2 = 0.f, a3 = 0.f;
        #pragma unroll
        for (int i = 0; i < 32; ++i) {
            const float4 wv = wreg[i];
            const int k = kb + 4 * i;
            const float4 h0 = *(const float4*)&h_lds[0 * HS + k];
            const float4 h1 = *(const float4*)&h_lds[1 * HS + k];
            const float4 h2 = *(const float4*)&h_lds[2 * HS + k];
            const float4 h3 = *(const float4*)&h_lds[3 * HS + k];
            a0 += wv.x * h0.x + wv.y * h0.y + wv.z * h0.z + wv.w * h0.w;
            a1 += wv.x * h1.x + wv.y * h1.y + wv.z * h1.z + wv.w * h1.w;
            a2 += wv.x * h2.x + wv.y * h2.y + wv.z * h2.z + wv.w * h2.w;
            a3 += wv.x * h3.x + wv.y * h3.y + wv.z * h3.z + wv.w * h3.w;
        }
        ((float4*)part)[q * GPW + g] = make_float4(a0, a1, a2, a3);
        if (t + 1 < TS && tid < RPG * NF) xl[(t + 1) & 1][xr][xk] = xpre;
        __syncthreads();  // #2: partials + x ready

        // reduce over q + x-projection + bias + activation; thread -> (g2 = tid>>2, r2 = tid&3)
        {
            const int g2 = tid >> 2, r2 = tid & 3;
            float v = part[0 * 512 + tid] + part[1 * 512 + tid] +
                      part[2 * 512 + tid] + part[3 * 512 + tid];
            const float* xrow = &xl[t & 1][r2][0];
            const float* wrow = &wcomb[g2][0];
            float s = 0.f;
            #pragma unroll
            for (int kk = 0; kk < NF; kk += 4) {
                const float4 xv = *(const float4*)(xrow + kk);
                const float4 wv = *(const float4*)(wrow + kk);
                s += xv.x * wv.x + xv.y * wv.y + xv.z * wv.z + xv.w * wv.w;
            }
            v += s + bcl[g2];
            // gate type (g2>>5) is wave-uniform: no divergence
            float a;
            if ((g2 >> 5) == 2) a = fast_tanh(v);      // cell gate
            else                a = fast_sigmoid(v);   // i,f,o
            gact[tid] = a;
        }
        __syncthreads();  // #3: gact ready

        // c/h update on tid<128 (waves 0,1): (r2 = tid&3, j2 = tid>>2)
        if (tid < 128) {
            const int r2 = tid & 3, j2 = tid >> 2;
            const float iv = gact[0 + tid], fv = gact[128 + tid];
            const float gv = gact[256 + tid], ov = gact[384 + tid];
            c_reg = fv * c_reg + iv * gv;
            const float h = ov * fast_tanh(c_reg);
            hsum += h;
            __hip_atomic_store(&hbuf[((size_t)(t & 1) * NB + grp * RPG + r2) * NH + slc * 32 + j2],
                               h, __ATOMIC_RELAXED, __HIP_MEMORY_SCOPE_AGENT);
            // publish: lane 0 of each writer wave waits its own stores' ack
            // (vmcnt(0)) then bumps the counter — no barrier, no cache ops.
            if ((tid & 63) == 0) {
                __builtin_amdgcn_s_waitcnt(0x0f70);  // vmcnt(0), ignore exp/lgkm
                __hip_atomic_fetch_add(&cnt[grp * TS + t], 1, __ATOMIC_RELAXED,
                                       __HIP_MEMORY_SCOPE_AGENT);
            }
        }
        // no trailing barrier: next iteration's spin + barrier #1 cover all
        // cross-wave hazards (h_lds rewrite only after all WGs published t,
        // which implies every wave here passed barrier #3).
    }

    if (tid < 128) {
        const int r2 = tid & 3, j2 = tid >> 2;
        pooled[(size_t)(grp * RPG + r2) * NH + slc * 32 + j2] = hsum * (1.f / TS);
    }
}

// out[b][o] = pooled[b]·W_fc[o] + b_fc[o]
__global__ __launch_bounds__(256) void k_fc(const float* __restrict__ pooled,
                                            const float* __restrict__ W_fc,
                                            const float* __restrict__ b_fc,
                                            float* __restrict__ out) {
    __shared__ float pl[2][NH];
    const int b0 = blockIdx.x * 2;
    for (int i = threadIdx.x; i < 2 * NH; i += 256)
        pl[i >> 9][i & 511] = pooled[(size_t)b0 * NH + i];
    __syncthreads();
    const int o = threadIdx.x & 127, bl = threadIdx.x >> 7;
    const float* wr = W_fc + (size_t)o * NH;
    float acc = 0.f;
    #pragma unroll 4
    for (int k = 0; k < NH; k += 4) {
        const float4 wv = *(const float4*)&wr[k];
        acc += pl[bl][k] * wv.x + pl[bl][k + 1] * wv.y +
               pl[bl][k + 2] * wv.z + pl[bl][k + 3] * wv.w;
    }
    out[(size_t)(b0 + bl) * NO + o] = acc + b_fc[o];
}

extern "C" void kernel_launch(void* const* d_in, const int* in_sizes, int n_in,
                              void* d_out, int out_size, void* d_ws, size_t ws_size,
                              hipStream_t stream) {
    const float* x     = (const float*)d_in[0];
    const float* W_emb = (const float*)d_in[1];
    const float* b_emb = (const float*)d_in[2];
    const float* W_ih  = (const float*)d_in[3];
    const float* W_hh  = (const float*)d_in[4];
    const float* b_ih  = (const float*)d_in[5];
    const float* b_hh  = (const float*)d_in[6];
    const float* W_fc  = (const float*)d_in[7];
    const float* b_fc  = (const float*)d_in[8];
    float* out = (float*)d_out;
    float* ws  = (float*)d_ws;

    float* W_comb = ws + OFF_WCOMB;
    float* b_comb = ws + OFF_BCOMB;
    float* hbuf   = ws + OFF_HBUF;
    float* pooled = ws + OFF_POOL;
    int*   cnt    = (int*)(ws + OFF_CNT);

    hipLaunchKernelGGL(k_zero,  dim3(32),  dim3(256), 0, stream, cnt);
    hipLaunchKernelGGL(k_wcomb, dim3(512), dim3(256), 0, stream,
                       W_emb, b_emb, W_ih, b_ih, b_hh, W_comb, b_comb);
    hipLaunchKernelGGL(k_lstm,  dim3(256), dim3(512), 0, stream,
                       x, W_hh, W_comb, b_comb, hbuf, pooled, cnt);
    hipLaunchKernelGGL(k_fc,    dim3(32),  dim3(256), 0, stream,
                       pooled, W_fc, b_fc, out);
}

// Round 4
// 2635.932 us; speedup vs baseline: 2.7898x; 1.7376x over previous
//
#include <hip/hip_runtime.h>
#include <math.h>

#define TS 512
#define NB 64
#define NF 64
#define NE 256
#define NH 512
#define NG 2048
#define NO 128

#define NGRP 16   // batch groups (4 rows each)
#define NSLC 16   // gate slices per group
#define RPG  4    // rows per group
#define GPW  128  // gate-rows per WG (4 gate types x 32 h-idx)
#define SA   520  // hA row stride in bf16 elements (512 + 8 pad)

// ws layout (float words)
#define OFF_WCOMB 0        // 2048*64
#define OFF_BCOMB 131072   // 2048
#define OFF_HBUF  133120   // 2*64*512
#define OFF_POOL  198656   // 64*512
#define OFF_CNT   231424   // 16*512 ints

typedef short bf16x8 __attribute__((ext_vector_type(8)));
typedef short bf16x4 __attribute__((ext_vector_type(4)));
typedef float f32x4 __attribute__((ext_vector_type(4)));

union F8 { bf16x8 s; unsigned short u[8]; };
union F4 { bf16x4 s; unsigned short u[4]; };

__device__ __forceinline__ unsigned short f2bf(float f) {
    unsigned u = __float_as_uint(f);
    u += 0x7fffu + ((u >> 16) & 1u);
    return (unsigned short)(u >> 16);
}
__device__ __forceinline__ float bf2f(unsigned short h) {
    return __uint_as_float(((unsigned)h) << 16);
}
__device__ __forceinline__ float fast_sigmoid(float v) {
    return 1.f / (1.f + __expf(-v));
}
__device__ __forceinline__ float fast_tanh(float v) {
    return 1.f - 2.f / (1.f + __expf(2.f * v));
}

__global__ __launch_bounds__(256) void k_zero(int* __restrict__ cnt) {
    int i = blockIdx.x * 256 + threadIdx.x;
    if (i < NGRP * TS) cnt[i] = 0;
}

// W_comb[g][f] = sum_e W_ih[g][e] * W_emb[e][f];  b_comb[g] = W_ih[g]·b_emb + b_ih[g] + b_hh[g]
__global__ __launch_bounds__(256) void k_wcomb(const float* __restrict__ W_emb,
                                               const float* __restrict__ b_emb,
                                               const float* __restrict__ W_ih,
                                               const float* __restrict__ b_ih,
                                               const float* __restrict__ b_hh,
                                               float* __restrict__ W_comb,
                                               float* __restrict__ b_comb) {
    __shared__ float wih[4][NE];
    int g0 = blockIdx.x * 4;
    for (int i = threadIdx.x; i < 4 * NE; i += 256)
        wih[i >> 8][i & 255] = W_ih[(size_t)g0 * NE + i];
    __syncthreads();
    int gl = threadIdx.x >> 6, f = threadIdx.x & 63;
    float acc = 0.f;
    for (int e = 0; e < NE; ++e) acc += wih[gl][e] * W_emb[e * NF + f];
    W_comb[(size_t)(g0 + gl) * NF + f] = acc;
    if (f == 0) {
        float a2 = 0.f;
        for (int e = 0; e < NE; ++e) a2 += wih[gl][e] * b_emb[e];
        b_comb[g0 + gl] = a2 + b_ih[g0 + gl] + b_hh[g0 + gl];
    }
}

// Persistent LSTM recurrence, MFMA edition. Grid 256 WGs x 512 thr (1/CU).
// Recurrent GEMM per WG per step: [4(pad 16) x 512] @ [512 x 128 gates] via
// mfma_f32_16x16x32_bf16, split-precision: W ~ Whi+Wlo, H ~ Hhi+Hlo (bf16),
// acc += Whi*Hhi + Whi*Hlo + Wlo*Hhi  (rel err ~2^-18, fp32-class).
// B-frags (weights) register-resident: 16 k-tiles x (hi+lo) x 4 VGPR = 128 VGPR.
// A-frags (h) from LDS, rows 4..15 zero via exec-masked loads.
__global__ __launch_bounds__(512, 2) void k_lstm(const float* __restrict__ x,
                                                 const float* __restrict__ W_hh,
                                                 const float* __restrict__ W_comb,
                                                 const float* __restrict__ b_comb,
                                                 float* __restrict__ hbuf,
                                                 float* __restrict__ pooled,
                                                 int* __restrict__ cnt) {
    const int wg = blockIdx.x;
    const int grp = wg & 15;
    const int slc = wg >> 4;
    const int tid = threadIdx.x;
    const int lane = tid & 63, wave = tid >> 6;
    const int m4 = lane & 15;          // A row / D col index
    const int qq = lane >> 4;          // quad

    __shared__ __align__(16) unsigned short hAhi[RPG * SA];
    __shared__ __align__(16) unsigned short hAlo[RPG * SA];
    __shared__ __align__(16) float part[GPW * 4];       // [gate][row]
    __shared__ float gact[512];                         // [gate][row]
    __shared__ __align__(16) float xl[2][RPG][68];
    __shared__ __align__(16) float wcomb[GPW][68];
    __shared__ float bcl[GPW];

    // ---- B-fragments: W_hh split-bf16, register-resident ----
    // wave covers gates g_loc = wave*16 + (lane&15); B[k][n]: lane n=lane&15,
    // k = kt*32 + qq*8 + j (j=0..7)
    const int g_loc = wave * 16 + m4;
    const int grow = (g_loc >> 5) * NH + slc * 32 + (g_loc & 31);
    F8 bhi[16], blo[16];
    #pragma unroll
    for (int kt = 0; kt < 16; ++kt) {
        const float* wp = W_hh + (size_t)grow * NH + kt * 32 + qq * 8;
        const float4 w0 = *(const float4*)wp;
        const float4 w1 = *(const float4*)(wp + 4);
        float wf[8] = {w0.x, w0.y, w0.z, w0.w, w1.x, w1.y, w1.z, w1.w};
        #pragma unroll
        for (int e = 0; e < 8; ++e) {
            unsigned short hb = f2bf(wf[e]);
            bhi[kt].u[e] = hb;
            blo[kt].u[e] = f2bf(wf[e] - bf2f(hb));
        }
    }

    // W_comb slice + b_comb slice
    for (int i = tid; i < GPW * NF; i += 512) {
        int gg = i >> 6, ff = i & 63;
        int Rg = (gg >> 5) * NH + slc * 32 + (gg & 31);
        wcomb[gg][ff] = W_comb[(size_t)Rg * NF + ff];
    }
    if (tid < GPW) {
        int Rg = (tid >> 5) * NH + slc * 32 + (tid & 31);
        bcl[tid] = b_comb[Rg];
    }
    // x[t=0]
    if (tid < RPG * NF) {
        int r = tid >> 6, k = tid & 63;
        xl[0][r][k] = x[((size_t)(grp * RPG + r) * TS + 0) * NF + k];
    }
    // zero hA (t=0 state)
    for (int i = tid; i < RPG * SA; i += 512) { hAhi[i] = 0; hAlo[i] = 0; }

    float c_reg = 0.f, hsum = 0.f;  // live on tid<128
    __syncthreads();

    for (int t = 0; t < TS; ++t) {
        if (t > 0) {
            // every wave's lane 0 spins (RELAXED — no cache maintenance)
            if ((tid & 63) == 0) {
                int guard = 0;
                while (__hip_atomic_load(&cnt[grp * TS + (t - 1)], __ATOMIC_RELAXED,
                                         __HIP_MEMORY_SCOPE_AGENT) < 2 * NSLC) {
                    __builtin_amdgcn_s_sleep(2);
                    if (++guard > (1 << 22)) break;  // anti-hang escape
                }
            }
            __builtin_amdgcn_fence(__ATOMIC_ACQUIRE, "workgroup");
            // stage h(t-1) -> LDS as split bf16 (hi, lo)
            {
                int r = tid >> 7, k4 = (tid & 127) << 2;
                const unsigned long long* hp = (const unsigned long long*)
                    (hbuf + ((size_t)((t - 1) & 1) * NB + grp * RPG + r) * NH + k4);
                union { unsigned long long u[2]; float f[4]; } hv;
                hv.u[0] = __hip_atomic_load(hp + 0, __ATOMIC_RELAXED, __HIP_MEMORY_SCOPE_AGENT);
                hv.u[1] = __hip_atomic_load(hp + 1, __ATOMIC_RELAXED, __HIP_MEMORY_SCOPE_AGENT);
                F4 phi, plo;
                #pragma unroll
                for (int e = 0; e < 4; ++e) {
                    unsigned short hb = f2bf(hv.f[e]);
                    phi.u[e] = hb;
                    plo.u[e] = f2bf(hv.f[e] - bf2f(hb));
                }
                *(bf16x4*)&hAhi[r * SA + k4] = phi.s;
                *(bf16x4*)&hAlo[r * SA + k4] = plo.s;
            }
        }
        // prefetch x[t+1] (independent of h)
        float xpre = 0.f; int xr = 0, xk = 0;
        if (t + 1 < TS && tid < RPG * NF) {
            xr = tid >> 6; xk = tid & 63;
            xpre = x[((size_t)(grp * RPG + xr) * TS + (t + 1)) * NF + xk];
        }
        __syncthreads();  // #1: hA ready

        // ---- MFMA: acc[m][n] = sum_k H[m][k] * W[n][k] ----
        f32x4 acc = {0.f, 0.f, 0.f, 0.f};
        {
            const int aoff = m4 * SA + qq * 8;  // valid when m4 < 4
            #pragma unroll
            for (int kt = 0; kt < 16; ++kt) {
                bf16x8 ah = {0, 0, 0, 0, 0, 0, 0, 0};
                bf16x8 al = {0, 0, 0, 0, 0, 0, 0, 0};
                if (m4 < RPG) {
                    ah = *(const bf16x8*)&hAhi[aoff + kt * 32];
                    al = *(const bf16x8*)&hAlo[aoff + kt * 32];
                }
                acc = __builtin_amdgcn_mfma_f32_16x16x32_bf16(ah, bhi[kt].s, acc, 0, 0, 0);
                acc = __builtin_amdgcn_mfma_f32_16x16x32_bf16(al, bhi[kt].s, acc, 0, 0, 0);
                acc = __builtin_amdgcn_mfma_f32_16x16x32_bf16(ah, blo[kt].s, acc, 0, 0, 0);
            }
        }
        // D rows 0..3 (real batch rows) live on quad 0, regs 0..3
        if (lane < 16)
            *(float4*)&part[(wave * 16 + lane) << 2] = make_float4(acc.x, acc.y, acc.z, acc.w);
        if (t + 1 < TS && tid < RPG * NF) xl[(t + 1) & 1][xr][xk] = xpre;
        __syncthreads();  // #2: part + x ready

        // x-projection + bias + activation; thread -> (g2 = tid>>2, r2 = tid&3)
        {
            const int g2 = tid >> 2, r2 = tid & 3;
            float v = part[tid];
            const float* xrow = &xl[t & 1][r2][0];
            const float* wrow = &wcomb[g2][0];
            float s = 0.f;
            #pragma unroll
            for (int kk = 0; kk < NF; kk += 4) {
                const float4 xv = *(const float4*)(xrow + kk);
                const float4 wv = *(const float4*)(wrow + kk);
                s += xv.x * wv.x + xv.y * wv.y + xv.z * wv.z + xv.w * wv.w;
            }
            v += s + bcl[g2];
            float a;
            if ((g2 >> 5) == 2) a = fast_tanh(v);      // cell gate
            else                a = fast_sigmoid(v);   // i,f,o
            gact[tid] = a;
        }
        __syncthreads();  // #3: gact ready

        // c/h update on tid<128 (waves 0,1): (r2 = tid&3, j2 = tid>>2)
        if (tid < 128) {
            const int r2 = tid & 3, j2 = tid >> 2;
            const float iv = gact[0 + tid], fv = gact[128 + tid];
            const float gv = gact[256 + tid], ov = gact[384 + tid];
            c_reg = fv * c_reg + iv * gv;
            const float h = ov * fast_tanh(c_reg);
            hsum += h;
            __hip_atomic_store(&hbuf[((size_t)(t & 1) * NB + grp * RPG + r2) * NH + slc * 32 + j2],
                               h, __ATOMIC_RELAXED, __HIP_MEMORY_SCOPE_AGENT);
            // publish: lane 0 of each writer wave waits its own stores' ack
            if ((tid & 63) == 0) {
                __builtin_amdgcn_s_waitcnt(0x0f70);  // vmcnt(0)
                __hip_atomic_fetch_add(&cnt[grp * TS + t], 1, __ATOMIC_RELAXED,
                                       __HIP_MEMORY_SCOPE_AGENT);
            }
        }
        // no trailing barrier: next iteration's spin + barrier #1 cover hazards
    }

    if (tid < 128) {
        const int r2 = tid & 3, j2 = tid >> 2;
        pooled[(size_t)(grp * RPG + r2) * NH + slc * 32 + j2] = hsum * (1.f / TS);
    }
}

// out[b][o] = pooled[b]·W_fc[o] + b_fc[o]
__global__ __launch_bounds__(256) void k_fc(const float* __restrict__ pooled,
                                            const float* __restrict__ W_fc,
                                            const float* __restrict__ b_fc,
                                            float* __restrict__ out) {
    __shared__ float pl[2][NH];
    const int b0 = blockIdx.x * 2;
    for (int i = threadIdx.x; i < 2 * NH; i += 256)
        pl[i >> 9][i & 511] = pooled[(size_t)b0 * NH + i];
    __syncthreads();
    const int o = threadIdx.x & 127, bl = threadIdx.x >> 7;
    const float* wr = W_fc + (size_t)o * NH;
    float acc = 0.f;
    #pragma unroll 4
    for (int k = 0; k < NH; k += 4) {
        const float4 wv = *(const float4*)&wr[k];
        acc += pl[bl][k] * wv.x + pl[bl][k + 1] * wv.y +
               pl[bl][k + 2] * wv.z + pl[bl][k + 3] * wv.w;
    }
    out[(size_t)(b0 + bl) * NO + o] = acc + b_fc[o];
}

extern "C" void kernel_launch(void* const* d_in, const int* in_sizes, int n_in,
                              void* d_out, int out_size, void* d_ws, size_t ws_size,
                              hipStream_t stream) {
    const float* x     = (const float*)d_in[0];
    const float* W_emb = (const float*)d_in[1];
    const float* b_emb = (const float*)d_in[2];
    const float* W_ih  = (const float*)d_in[3];
    const float* W_hh  = (const float*)d_in[4];
    const float* b_ih  = (const float*)d_in[5];
    const float* b_hh  = (const float*)d_in[6];
    const float* W_fc  = (const float*)d_in[7];
    const float* b_fc  = (const float*)d_in[8];
    float* out = (float*)d_out;
    float* ws  = (float*)d_ws;

    float* W_comb = ws + OFF_WCOMB;
    float* b_comb = ws + OFF_BCOMB;
    float* hbuf   = ws + OFF_HBUF;
    float* pooled = ws + OFF_POOL;
    int*   cnt    = (int*)(ws + OFF_CNT);

    hipLaunchKernelGGL(k_zero,  dim3(32),  dim3(256), 0, stream, cnt);
    hipLaunchKernelGGL(k_wcomb, dim3(512), dim3(256), 0, stream,
                       W_emb, b_emb, W_ih, b_ih, b_hh, W_comb, b_comb);
    hipLaunchKernelGGL(k_lstm,  dim3(256), dim3(512), 0, stream,
                       x, W_hh, W_comb, b_comb, hbuf, pooled, cnt);
    hipLaunchKernelGGL(k_fc,    dim3(32),  dim3(256), 0, stream,
                       pooled, W_fc, b_fc, out);
}

// Round 5
// 2063.976 us; speedup vs baseline: 3.5628x; 1.2771x over previous
//
#include <hip/hip_runtime.h>
#include <math.h>

#define TS 512
#define NB 64
#define NF 64
#define NE 256
#define NH 512
#define NG 2048
#define NO 128

#define NGRP 16   // batch groups (4 rows each)
#define NSLC 16   // gate slices per group
#define RPG  4    // rows per group
#define GPW  128  // gate-rows per WG (4 gate types x 32 h-idx)
#define NK   576  // k-dim: 512 h + 64 x
#define NKT  18   // k-tiles of 32
#define SA   584  // hA row stride in bf16 elements (576 + 8 pad)

// ws layout (float words)
#define OFF_WCOMB 0        // 2048*64
#define OFF_BCOMB 131072   // 2048
#define OFF_HBUF  133120   // 2*64*512 (packed u32: hi bf16 <<16 | lo bf16)
#define OFF_POOL  198656   // 64*512
#define OFF_CNT   231424   // 16*512 ints

typedef short bf16x8 __attribute__((ext_vector_type(8)));
typedef short bf16x4 __attribute__((ext_vector_type(4)));
typedef float f32x4 __attribute__((ext_vector_type(4)));

union F8 { bf16x8 s; unsigned short u[8]; };
union F4 { bf16x4 s; unsigned short u[4]; };

__device__ __forceinline__ unsigned short f2bf(float f) {
    unsigned u = __float_as_uint(f);
    u += 0x7fffu + ((u >> 16) & 1u);
    return (unsigned short)(u >> 16);
}
__device__ __forceinline__ float bf2f(unsigned short h) {
    return __uint_as_float(((unsigned)h) << 16);
}
__device__ __forceinline__ float fast_sigmoid(float v) {
    return 1.f / (1.f + __expf(-v));
}
__device__ __forceinline__ float fast_tanh(float v) {
    return 1.f - 2.f / (1.f + __expf(2.f * v));
}

__global__ __launch_bounds__(256) void k_zero(int* __restrict__ cnt) {
    int i = blockIdx.x * 256 + threadIdx.x;
    if (i < NGRP * TS) cnt[i] = 0;
}

// W_comb[g][f] = sum_e W_ih[g][e] * W_emb[e][f];  b_comb[g] = W_ih[g]·b_emb + b_ih[g] + b_hh[g]
__global__ __launch_bounds__(256) void k_wcomb(const float* __restrict__ W_emb,
                                               const float* __restrict__ b_emb,
                                               const float* __restrict__ W_ih,
                                               const float* __restrict__ b_ih,
                                               const float* __restrict__ b_hh,
                                               float* __restrict__ W_comb,
                                               float* __restrict__ b_comb) {
    __shared__ float wih[4][NE];
    int g0 = blockIdx.x * 4;
    for (int i = threadIdx.x; i < 4 * NE; i += 256)
        wih[i >> 8][i & 255] = W_ih[(size_t)g0 * NE + i];
    __syncthreads();
    int gl = threadIdx.x >> 6, f = threadIdx.x & 63;
    float acc = 0.f;
    for (int e = 0; e < NE; ++e) acc += wih[gl][e] * W_emb[e * NF + f];
    W_comb[(size_t)(g0 + gl) * NF + f] = acc;
    if (f == 0) {
        float a2 = 0.f;
        for (int e = 0; e < NE; ++e) a2 += wih[gl][e] * b_emb[e];
        b_comb[g0 + gl] = a2 + b_ih[g0 + gl] + b_hh[g0 + gl];
    }
}

// Persistent LSTM recurrence, MFMA edition, x folded into k-dim.
// Per WG per step: [4(pad 16) x 576] @ [576 x 128] via mfma_f32_16x16x32_bf16,
// split-precision (3 accumulator chains: hi*hi, lo*hi, hi*lo).
// k 0..511 = h(t-1) (split bf16 from packed u32 exchange), k 512..575 = x(t),
// B tiles 0..15 from W_hh, 16..17 from W_comb. All B-frags register-resident.
__global__ __launch_bounds__(512, 2) void k_lstm(const float* __restrict__ x,
                                                 const float* __restrict__ W_hh,
                                                 const float* __restrict__ W_comb,
                                                 const float* __restrict__ b_comb,
                                                 unsigned int* __restrict__ hbuf,
                                                 float* __restrict__ pooled,
                                                 int* __restrict__ cnt) {
    const int wg = blockIdx.x;
    const int grp = wg & 15;
    const int slc = wg >> 4;
    const int tid = threadIdx.x;
    const int lane = tid & 63, wave = tid >> 6;
    const int m4 = lane & 15;          // A row / D col index
    const int qq = lane >> 4;          // quad

    __shared__ __align__(16) unsigned short hAhi[RPG * SA];
    __shared__ __align__(16) unsigned short hAlo[RPG * SA];
    __shared__ __align__(16) float part[GPW * 4];       // [gate][row]
    __shared__ float gact[512];                         // [gate][row]
    __shared__ float bcl[GPW];

    // ---- B-fragments: W_hh (tiles 0..15) + W_comb (tiles 16..17), split bf16 ----
    const int g_loc = wave * 16 + m4;
    const int grow = (g_loc >> 5) * NH + slc * 32 + (g_loc & 31);
    F8 bhi[NKT], blo[NKT];
    #pragma unroll
    for (int kt = 0; kt < 16; ++kt) {
        const float* wp = W_hh + (size_t)grow * NH + kt * 32 + qq * 8;
        const float4 w0 = *(const float4*)wp;
        const float4 w1 = *(const float4*)(wp + 4);
        float wf[8] = {w0.x, w0.y, w0.z, w0.w, w1.x, w1.y, w1.z, w1.w};
        #pragma unroll
        for (int e = 0; e < 8; ++e) {
            unsigned short hb = f2bf(wf[e]);
            bhi[kt].u[e] = hb;
            blo[kt].u[e] = f2bf(wf[e] - bf2f(hb));
        }
    }
    #pragma unroll
    for (int kt = 16; kt < NKT; ++kt) {
        const float* wp = W_comb + (size_t)grow * NF + (kt - 16) * 32 + qq * 8;
        const float4 w0 = *(const float4*)wp;
        const float4 w1 = *(const float4*)(wp + 4);
        float wf[8] = {w0.x, w0.y, w0.z, w0.w, w1.x, w1.y, w1.z, w1.w};
        #pragma unroll
        for (int e = 0; e < 8; ++e) {
            unsigned short hb = f2bf(wf[e]);
            bhi[kt].u[e] = hb;
            blo[kt].u[e] = f2bf(wf[e] - bf2f(hb));
        }
    }

    if (tid < GPW) {
        int Rg = (tid >> 5) * NH + slc * 32 + (tid & 31);
        bcl[tid] = b_comb[Rg];
    }
    // zero h-section of hA (cols 0..511); x-section written separately below
    for (int i = tid; i < RPG * NH; i += 512) {
        int r = i >> 9, c = i & 511;
        hAhi[r * SA + c] = 0;
        hAlo[r * SA + c] = 0;
    }
    // stage x(0) into x-section (cols 512..575): tid<64, float4 each
    if (tid < 64) {
        const int r = tid >> 4, k4 = (tid & 15) << 2;
        const float4 xv = *(const float4*)&x[((size_t)(grp * RPG + r) * TS + 0) * NF + k4];
        float xf[4] = {xv.x, xv.y, xv.z, xv.w};
        F4 phi, plo;
        #pragma unroll
        for (int e = 0; e < 4; ++e) {
            unsigned short hb = f2bf(xf[e]);
            phi.u[e] = hb;
            plo.u[e] = f2bf(xf[e] - bf2f(hb));
        }
        *(bf16x4*)&hAhi[r * SA + NH + k4] = phi.s;
        *(bf16x4*)&hAlo[r * SA + NH + k4] = plo.s;
    }

    float c_reg = 0.f, hsum = 0.f;  // live on tid<128
    float4 xpre = make_float4(0.f, 0.f, 0.f, 0.f);  // x(t+1), tid<64
    __syncthreads();

    for (int t = 0; t < TS; ++t) {
        if (t > 0) {
            // every wave's lane 0 spins (RELAXED — no cache maintenance)
            if ((tid & 63) == 0) {
                int guard = 0;
                while (__hip_atomic_load(&cnt[grp * TS + (t - 1)], __ATOMIC_RELAXED,
                                         __HIP_MEMORY_SCOPE_AGENT) < 2 * NSLC) {
                    __builtin_amdgcn_s_sleep(2);
                    if (++guard > (1 << 22)) break;  // anti-hang escape
                }
            }
            __builtin_amdgcn_fence(__ATOMIC_ACQUIRE, "workgroup");
            // stage h(t-1) -> LDS: packed u32 -> (hi,lo) bf16
            {
                int r = tid >> 7, k4 = (tid & 127) << 2;
                const unsigned long long* hp = (const unsigned long long*)
                    (hbuf + ((size_t)((t - 1) & 1) * NB + grp * RPG + r) * NH + k4);
                union { unsigned long long u64[2]; unsigned int u[4]; } hv;
                hv.u64[0] = __hip_atomic_load(hp + 0, __ATOMIC_RELAXED, __HIP_MEMORY_SCOPE_AGENT);
                hv.u64[1] = __hip_atomic_load(hp + 1, __ATOMIC_RELAXED, __HIP_MEMORY_SCOPE_AGENT);
                F4 phi, plo;
                #pragma unroll
                for (int e = 0; e < 4; ++e) {
                    phi.u[e] = (unsigned short)(hv.u[e] >> 16);
                    plo.u[e] = (unsigned short)(hv.u[e] & 0xffffu);
                }
                *(bf16x4*)&hAhi[r * SA + k4] = phi.s;
                *(bf16x4*)&hAlo[r * SA + k4] = plo.s;
            }
            // stage x(t) from prefetch regs (tid<64)
            if (tid < 64) {
                const int r = tid >> 4, k4 = (tid & 15) << 2;
                float xf[4] = {xpre.x, xpre.y, xpre.z, xpre.w};
                F4 phi, plo;
                #pragma unroll
                for (int e = 0; e < 4; ++e) {
                    unsigned short hb = f2bf(xf[e]);
                    phi.u[e] = hb;
                    plo.u[e] = f2bf(xf[e] - bf2f(hb));
                }
                *(bf16x4*)&hAhi[r * SA + NH + k4] = phi.s;
                *(bf16x4*)&hAlo[r * SA + NH + k4] = plo.s;
            }
        }
        // prefetch x(t+1) (independent of h)
        if (t + 1 < TS && tid < 64) {
            const int r = tid >> 4, k4 = (tid & 15) << 2;
            xpre = *(const float4*)&x[((size_t)(grp * RPG + r) * TS + (t + 1)) * NF + k4];
        }
        __syncthreads();  // #1: hA ready

        // ---- MFMA: acc[m][n] = sum_k A[m][k] * W[n][k], 3 independent chains ----
        f32x4 acc0 = {0.f, 0.f, 0.f, 0.f};
        f32x4 acc1 = {0.f, 0.f, 0.f, 0.f};
        f32x4 acc2 = {0.f, 0.f, 0.f, 0.f};
        {
            const int aoff = m4 * SA + qq * 8;  // valid when m4 < 4
            #pragma unroll
            for (int kt = 0; kt < NKT; ++kt) {
                bf16x8 ah = {0, 0, 0, 0, 0, 0, 0, 0};
                bf16x8 al = {0, 0, 0, 0, 0, 0, 0, 0};
                if (m4 < RPG) {
                    ah = *(const bf16x8*)&hAhi[aoff + kt * 32];
                    al = *(const bf16x8*)&hAlo[aoff + kt * 32];
                }
                acc0 = __builtin_amdgcn_mfma_f32_16x16x32_bf16(ah, bhi[kt].s, acc0, 0, 0, 0);
                acc1 = __builtin_amdgcn_mfma_f32_16x16x32_bf16(al, bhi[kt].s, acc1, 0, 0, 0);
                acc2 = __builtin_amdgcn_mfma_f32_16x16x32_bf16(ah, blo[kt].s, acc2, 0, 0, 0);
            }
        }
        // D rows 0..3 (real batch rows) live on quad 0, regs 0..3
        if (lane < 16) {
            f32x4 acc = acc0 + acc1 + acc2;
            *(float4*)&part[(wave * 16 + lane) << 2] = make_float4(acc.x, acc.y, acc.z, acc.w);
        }
        __syncthreads();  // #2: part ready

        // bias + activation; thread -> (g2 = tid>>2, r2 = tid&3)
        {
            const int g2 = tid >> 2;
            const float v = part[tid] + bcl[g2];
            float a;
            if ((g2 >> 5) == 2) a = fast_tanh(v);      // cell gate
            else                a = fast_sigmoid(v);   // i,f,o
            gact[tid] = a;
        }
        __syncthreads();  // #3: gact ready

        // c/h update on tid<128 (waves 0,1): (r2 = tid&3, j2 = tid>>2)
        if (tid < 128) {
            const int r2 = tid & 3, j2 = tid >> 2;
            const float iv = gact[0 + tid], fv = gact[128 + tid];
            const float gv = gact[256 + tid], ov = gact[384 + tid];
            c_reg = fv * c_reg + iv * gv;
            const float h = ov * fast_tanh(c_reg);
            hsum += h;
            // pack split-bf16 once (producer-side): hi<<16 | lo
            const unsigned short hb = f2bf(h);
            const unsigned short lb = f2bf(h - bf2f(hb));
            const unsigned int pk = ((unsigned int)hb << 16) | lb;
            __hip_atomic_store(&hbuf[((size_t)(t & 1) * NB + grp * RPG + r2) * NH + slc * 32 + j2],
                               pk, __ATOMIC_RELAXED, __HIP_MEMORY_SCOPE_AGENT);
            // publish: lane 0 of each writer wave waits its own stores' ack
            if ((tid & 63) == 0) {
                __builtin_amdgcn_s_waitcnt(0x0f70);  // vmcnt(0)
                __hip_atomic_fetch_add(&cnt[grp * TS + t], 1, __ATOMIC_RELAXED,
                                       __HIP_MEMORY_SCOPE_AGENT);
            }
        }
        // no trailing barrier: next iteration's spin + barrier #1 cover hazards
    }

    if (tid < 128) {
        const int r2 = tid & 3, j2 = tid >> 2;
        pooled[(size_t)(grp * RPG + r2) * NH + slc * 32 + j2] = hsum * (1.f / TS);
    }
}

// out[b][o] = pooled[b]·W_fc[o] + b_fc[o]
__global__ __launch_bounds__(256) void k_fc(const float* __restrict__ pooled,
                                            const float* __restrict__ W_fc,
                                            const float* __restrict__ b_fc,
                                            float* __restrict__ out) {
    __shared__ float pl[2][NH];
    const int b0 = blockIdx.x * 2;
    for (int i = threadIdx.x; i < 2 * NH; i += 256)
        pl[i >> 9][i & 511] = pooled[(size_t)b0 * NH + i];
    __syncthreads();
    const int o = threadIdx.x & 127, bl = threadIdx.x >> 7;
    const float* wr = W_fc + (size_t)o * NH;
    float acc = 0.f;
    #pragma unroll 4
    for (int k = 0; k < NH; k += 4) {
        const float4 wv = *(const float4*)&wr[k];
        acc += pl[bl][k] * wv.x + pl[bl][k + 1] * wv.y +
               pl[bl][k + 2] * wv.z + pl[bl][k + 3] * wv.w;
    }
    out[(size_t)(b0 + bl) * NO + o] = acc + b_fc[o];
}

extern "C" void kernel_launch(void* const* d_in, const int* in_sizes, int n_in,
                              void* d_out, int out_size, void* d_ws, size_t ws_size,
                              hipStream_t stream) {
    const float* x     = (const float*)d_in[0];
    const float* W_emb = (const float*)d_in[1];
    const float* b_emb = (const float*)d_in[2];
    const float* W_ih  = (const float*)d_in[3];
    const float* W_hh  = (const float*)d_in[4];
    const float* b_ih  = (const float*)d_in[5];
    const float* b_hh  = (const float*)d_in[6];
    const float* W_fc  = (const float*)d_in[7];
    const float* b_fc  = (const float*)d_in[8];
    float* out = (float*)d_out;
    float* ws  = (float*)d_ws;

    float* W_comb = ws + OFF_WCOMB;
    float* b_comb = ws + OFF_BCOMB;
    unsigned int* hbuf = (unsigned int*)(ws + OFF_HBUF);
    float* pooled = ws + OFF_POOL;
    int*   cnt    = (int*)(ws + OFF_CNT);

    hipLaunchKernelGGL(k_zero,  dim3(32),  dim3(256), 0, stream, cnt);
    hipLaunchKernelGGL(k_wcomb, dim3(512), dim3(256), 0, stream,
                       W_emb, b_emb, W_ih, b_ih, b_hh, W_comb, b_comb);
    hipLaunchKernelGGL(k_lstm,  dim3(256), dim3(512), 0, stream,
                       x, W_hh, W_comb, b_comb, hbuf, pooled, cnt);
    hipLaunchKernelGGL(k_fc,    dim3(32),  dim3(256), 0, stream,
                       pooled, W_fc, b_fc, out);
}